// Round 23
// baseline (178.110 us; speedup 1.0000x reference)
//
#include <hip/hip_runtime.h>

typedef _Float16 f16;
typedef __attribute__((ext_vector_type(8))) _Float16 h8;
typedef __attribute__((ext_vector_type(4))) _Float16 h4;
typedef __attribute__((ext_vector_type(8))) short s8;     // 8 bf16 (4 VGPRs)
typedef __attribute__((ext_vector_type(4))) unsigned short u16x4;
typedef __attribute__((ext_vector_type(4))) float f4;
typedef __attribute__((ext_vector_type(16))) float f16x;
typedef __attribute__((ext_vector_type(4))) unsigned u4;

#define MFMA(a, b, c) __builtin_amdgcn_mfma_f32_16x16x32_f16(a, b, c, 0, 0, 0)
#define MFMA32(a, b, c) __builtin_amdgcn_mfma_f32_32x32x16_f16(a, b, c, 0, 0, 0)
#define MFMA32B(a, b, c) __builtin_amdgcn_mfma_f32_32x32x16_bf16(a, b, c, 0, 0, 0)

// Q prescale: 1/sqrt(64) * log2(e), folded into qkv epilogue -> softmax in base-2
#define QSCALE 0.18033688011112042f

#define ASM_VMCNT(N) asm volatile("s_waitcnt vmcnt(" #N ")" ::: "memory")

__device__ __forceinline__ void gload16(const void* g, void* l) {
    __builtin_amdgcn_global_load_lds((const __attribute__((address_space(1))) void*)g,
                                     (__attribute__((address_space(3))) void*)l, 16, 0, 0);
}

__device__ __forceinline__ float fexp2(float x) {
    float r;
    asm("v_exp_f32 %0, %1" : "=v"(r) : "v"(x));
    return r;
}

// pack 2 f32 -> 2 bf16 in one u32 (low = src0)
__device__ __forceinline__ unsigned pkb(float a, float b) {
    unsigned r;
    asm("v_cvt_pk_bf16_f32 %0, %1, %2" : "=v"(r) : "v"(a), "v"(b));
    return r;
}

// f32 -> bf16 with round-to-nearest-even
__device__ __forceinline__ unsigned short bf16rn(float x) {
    unsigned u = __builtin_bit_cast(unsigned, x);
    u += 0x7fffu + ((u >> 16) & 1u);
    return (unsigned short)(u >> 16);
}

// v_permlane32_swap_b32: a[l>=32] <-> b[l<32]  (both operands modified)
__device__ __forceinline__ void plswap(unsigned& a, unsigned& b) {
    asm volatile("v_permlane32_swap_b32 %0, %1" : "+v"(a), "+v"(b));
}

// ---------------- conversion kernels ----------------

__global__ __launch_bounds__(256) void cvt_f16_kernel(const float* __restrict__ in,
                                                      f16* __restrict__ out, int n8) {
    int i = blockIdx.x * blockDim.x + threadIdx.x;
    if (i >= n8) return;
    const float4* p = (const float4*)in + (size_t)i * 2;
    float4 a = p[0], b = p[1];
    h8 o;
    o[0] = (f16)a.x; o[1] = (f16)a.y; o[2] = (f16)a.z; o[3] = (f16)a.w;
    o[4] = (f16)b.x; o[5] = (f16)b.y; o[6] = (f16)b.z; o[7] = (f16)b.w;
    *((h8*)out + i) = o;
}

// in: [R][Cc] f32 row-major -> out: [Cc][R] f16 row-major
__global__ __launch_bounds__(256) void transpose_cvt(const float* __restrict__ in,
                                                     f16* __restrict__ out, int R, int Cc) {
    __shared__ float tile[32][33];
    int tx = threadIdx.x, ty = threadIdx.y;
    int c0 = blockIdx.x * 32, r0 = blockIdx.y * 32;
#pragma unroll
    for (int k = 0; k < 32; k += 8)
        tile[ty + k][tx] = in[(size_t)(r0 + ty + k) * Cc + c0 + tx];
    __syncthreads();
#pragma unroll
    for (int k = 0; k < 32; k += 8)
        out[(size_t)(c0 + ty + k) * R + r0 + tx] = (f16)tile[tx][ty + k];
}

// ---------------- GEMM core: 128x128 tile, BK=64, 4 waves, 2-phase + stage-under-MFMA ----------
// Double-buffered LDS (2 x 32KB). Per K-step:
//   vmcnt(0)   -- tile-t's 8 loads (issued UNDER step t-1's MFMAs) have landed
//   s_barrier  -- all waves see buf[cur] full
//   { ds_read kk frags; issue stage-half(t+1 -> buf[other]); 16 MFMA } x2   <- issue overlap
//   lgkmcnt(0); s_barrier  -- all reads of buf[cur] done before t+1 re-stages it
// Safety: barrier-2 of step t-1 guarantees buf[other] is no longer being read when step t
// stages into it. t+1's loads stay in flight across BOTH barriers (counted-vmcnt property).

__device__ __forceinline__ void gemm_stage_half(const f16* __restrict__ M, int K, int r0, int k0,
                                                f16* dst, int tid, int wave) {
#pragma unroll
    for (int i = 0; i < 4; i++) {
        int s = i * 256 + tid;
        int row = s >> 3;
        int gc = ((s & 7) ^ (row & 7)) * 8;
        gload16(M + (size_t)(r0 + row) * K + k0 + gc, dst + (i * 256 + wave * 64) * 8);
    }
}

__device__ __forceinline__ void gemm_step(const f16* __restrict__ A, const f16* __restrict__ Bt,
                                          int K, int m0, int n0, int t, int nt,
                                          const f16* cA, const f16* cB, f16* nA, f16* nB,
                                          int tid, int lane, int wave, int wm, int wn,
                                          f4 acc[4][4]) {
    ASM_VMCNT(0);  // exactly tile-t's 8 loads are outstanding here
    __builtin_amdgcn_sched_barrier(0);
    __builtin_amdgcn_s_barrier();
    __builtin_amdgcn_sched_barrier(0);
    const bool stage = (t + 1 < nt);
#pragma unroll
    for (int kk = 0; kk < 2; kk++) {
        h8 af[4], bg[4];
#pragma unroll
        for (int im = 0; im < 4; im++) {
            int row = wm + im * 16 + (lane & 15);
            int pc = (kk * 4 + (lane >> 4)) ^ (row & 7);
            af[im] = *(const h8*)(cA + row * 64 + pc * 8);
        }
#pragma unroll
        for (int in = 0; in < 4; in++) {
            int row = wn + in * 16 + (lane & 15);
            int pc = (kk * 4 + (lane >> 4)) ^ (row & 7);
            bg[in] = *(const h8*)(cB + row * 64 + pc * 8);
        }
        if (stage) {  // issue next-tile loads under this kk's MFMAs
            if (kk == 0) gemm_stage_half(A, K, m0, (t + 1) * 64, nA, tid, wave);
            else         gemm_stage_half(Bt, K, n0, (t + 1) * 64, nB, tid, wave);
        }
        __builtin_amdgcn_s_setprio(1);
#pragma unroll
        for (int im = 0; im < 4; im++)
#pragma unroll
            for (int in = 0; in < 4; in++)
                acc[im][in] = MFMA(af[im], bg[in], acc[im][in]);
        __builtin_amdgcn_s_setprio(0);
    }
    // all this wave's ds_reads of buf[cur] retired before signalling
    asm volatile("s_waitcnt lgkmcnt(0)" ::: "memory");
    __builtin_amdgcn_sched_barrier(0);
    __builtin_amdgcn_s_barrier();
    __builtin_amdgcn_sched_barrier(0);
}

__device__ __forceinline__ void gemm_core(const f16* __restrict__ A, const f16* __restrict__ Bt,
                                          int K, int m0, int n0,
                                          f16* lA0, f16* lB0, f16* lA1, f16* lB1,
                                          f4 acc[4][4]) {
    const int tid = threadIdx.x, lane = tid & 63, wave = tid >> 6;
    const int wm = (wave >> 1) * 64, wn = (wave & 1) * 64;
    const int nt = K >> 6;  // 16 (even) for K=1024

    // prologue: stage tile 0 into buf 0 (completion enforced by step-0's vmcnt(0))
    gemm_stage_half(A, K, m0, 0, lA0, tid, wave);
    gemm_stage_half(Bt, K, n0, 0, lB0, tid, wave);

    for (int t = 0; t < nt; t += 2) {
        gemm_step(A, Bt, K, m0, n0, t, nt, lA0, lB0, lA1, lB1, tid, lane, wave, wm, wn, acc);
        gemm_step(A, Bt, K, m0, n0, t + 1, nt, lA1, lB1, lA0, lB0, tid, lane, wave, wm, wn, acc);
    }
}

// ---------------- QKV GEMM: Q (prescaled), K [BH][T][64] f16; V [BH][T/32][64][32] bf16 ----------------

__global__ __launch_bounds__(256) void qkv_gemm(const f16* __restrict__ A, const f16* __restrict__ Bt,
                                                const float* __restrict__ bias,
                                                f16* __restrict__ Qo, f16* __restrict__ Ko,
                                                unsigned short* __restrict__ Vo) {
    __shared__ f16 lA[2][128 * 64], lB[2][128 * 64];
    f4 acc[4][4];
    const f4 zz = {0.f, 0.f, 0.f, 0.f};
#pragma unroll
    for (int i = 0; i < 4; i++)
#pragma unroll
        for (int j = 0; j < 4; j++) acc[i][j] = zz;

    const int swz = (blockIdx.x & 7) * 192 + (blockIdx.x >> 3);  // XCD-chunked (1536 = 8*192)
    const int nb = swz % 24, mb = swz / 24;
    gemm_core(A, Bt, 1024, mb * 128, nb * 128, lA[0], lB[0], lA[1], lB[1], acc);

    const int lane = threadIdx.x & 63, wave = threadIdx.x >> 6;
    const int wm = (wave >> 1) * 64, wn = (wave & 1) * 64;
#pragma unroll
    for (int im = 0; im < 4; im++) {
        int m4 = mb * 128 + wm + im * 16 + (lane >> 4) * 4;
        int b = m4 >> 11, t0 = m4 & 2047;
#pragma unroll
        for (int in = 0; in < 4; in++) {
            int n = nb * 128 + wn + in * 16 + (lane & 15);
            float bb = bias[n];
            int sec = n >> 10, cc = n & 1023, hh = cc >> 6, d = cc & 63;
            if (sec == 2) {
                // V tiled [kt][64][32] bf16: addr = bh*131072 + (t/32)*2048 + d*32 + (t&31)
                u16x4 pv;
#pragma unroll
                for (int r = 0; r < 4; r++) pv[r] = bf16rn(acc[im][in][r] + bb);
                *(u16x4*)(Vo + (size_t)(b * 16 + hh) * 131072 + (t0 >> 5) * 2048 + d * 32 +
                          (t0 & 31)) = pv;
            } else {
                f16* dst = sec ? Ko : Qo;
                float sc = sec ? 1.0f : QSCALE;  // Q prescaled for base-2 softmax
                size_t base = ((size_t)(b * 16 + hh) * 2048 + t0) * 64 + d;
#pragma unroll
                for (int r = 0; r < 4; r++)
                    dst[base + (size_t)r * 64] = (f16)((acc[im][in][r] + bb) * sc);
            }
        }
    }
}

// ---------------- Proj GEMM: f32 output + bias ----------------

__global__ __launch_bounds__(256) void proj_gemm(const f16* __restrict__ A, const f16* __restrict__ Bt,
                                                 const float* __restrict__ bias,
                                                 float* __restrict__ out) {
    __shared__ f16 lA[2][128 * 64], lB[2][128 * 64];
    f4 acc[4][4];
    const f4 zz = {0.f, 0.f, 0.f, 0.f};
#pragma unroll
    for (int i = 0; i < 4; i++)
#pragma unroll
        for (int j = 0; j < 4; j++) acc[i][j] = zz;

    const int swz = (blockIdx.x & 7) * 64 + (blockIdx.x >> 3);  // XCD-chunked (512 = 8*64)
    const int nb = swz & 7, mb = swz >> 3;
    gemm_core(A, Bt, 1024, mb * 128, nb * 128, lA[0], lB[0], lA[1], lB[1], acc);

    const int lane = threadIdx.x & 63, wave = threadIdx.x >> 6;
    const int wm = (wave >> 1) * 64, wn = (wave & 1) * 64;
#pragma unroll
    for (int im = 0; im < 4; im++) {
        int m4 = mb * 128 + wm + im * 16 + (lane >> 4) * 4;
#pragma unroll
        for (int in = 0; in < 4; in++) {
            int n = nb * 128 + wn + in * 16 + (lane & 15);
            float bb = bias[n];
#pragma unroll
            for (int r = 0; r < 4; r++)
                out[(size_t)(m4 + r) * 1024 + n] = acc[im][in][r] + bb;
        }
    }
}

// ---------------- Flash attention: R21 winner (R18 packaging + kt-tiled V) ----------------

__device__ __forceinline__ void attn_tile(int k0, bool last, bool stage_next,
                                          int lane, int hi, int ln,
                                          const f16* __restrict__ Kb,
                                          const unsigned short* __restrict__ Vb,
                                          const f16* lKcur, f16* lKnxt,
                                          const h8 (&qf)[4], s8 (&vf)[2][2], s8 (&vfn)[2][2],
                                          float& lpart, f16x& y0, f16x& y1) {
    if (stage_next) {
        // K(it+1) -> other LDS buffer (4 x gload16)
#pragma unroll
        for (int i = 0; i < 4; i++) {
            int s = i * 64 + lane;
            int row = s >> 3;
            int gc = ((s & 7) ^ (row & 7)) * 8;
            gload16(Kb + (size_t)(k0 + 32 + row) * 64 + gc, lKnxt + i * 512);
        }
        // V(it+1) -> other register set (4 x dwordx4); kt-tiled: lane-consecutive lines
#pragma unroll
        for (int ks = 0; ks < 2; ks++)
#pragma unroll
            for (int j = 0; j < 2; j++)
                vfn[ks][j] = *(const s8*)(Vb + (size_t)((k0 >> 5) + 1) * 2048 +
                                          (j * 32 + ln) * 32 + ks * 16 + hi * 8);
        ASM_VMCNT(8);  // wait only last tile's 8 loads; current 8 stay in flight
    } else {
        ASM_VMCNT(0);
    }
    __builtin_amdgcn_sched_barrier(0);

    // S^T = K.Q^T (A = K rows from LDS, B = Q regs); lane owns q = qw+ln
    f16x s0;
#pragma unroll
    for (int r = 0; r < 16; r++) s0[r] = 0.f;
    __builtin_amdgcn_s_setprio(1);
#pragma unroll
    for (int dd = 0; dd < 4; dd++) {
        const int c = (dd * 2 + hi) ^ (ln & 7);  // swizzled 16B-chunk index
        h8 ka = *(const h8*)(lKcur + ln * 64 + c * 8);
        s0 = MFMA32(ka, qf[dd], s0);
    }
    __builtin_amdgcn_s_setprio(0);

    if (last) {  // diagonal tile (k0 == qw): mask k-local kl > ln
#pragma unroll
        for (int r = 0; r < 16; r++) {
            int kl = (r & 3) + 8 * (r >> 2) + 4 * hi;
            if (kl > ln) s0[r] = -3e38f;
        }
    }

    // no-shift softmax: P = 2^S (bf16 keeps relative precision at any scale)
    float ls = 0.f;
#pragma unroll
    for (int r = 0; r < 16; r++) {
        float p = fexp2(s0[r]);
        s0[r] = p;
        ls += p;
    }
    lpart += ls;

    // P -> PV A-fragments (bf16): 8 cvt_pk_bf16 + 4 permlane32_swap (layout HW-verified R9)
    s8 pa[2];
    {
        unsigned a0 = pkb(s0[0], s0[1]), a1 = pkb(s0[2], s0[3]);
        unsigned b0 = pkb(s0[4], s0[5]), b1 = pkb(s0[6], s0[7]);
        plswap(a0, b0); plswap(a1, b1);
        u4 w0; w0[0] = a0; w0[1] = a1; w0[2] = b0; w0[3] = b1;
        pa[0] = __builtin_bit_cast(s8, w0);
        unsigned c0 = pkb(s0[8], s0[9]), c1 = pkb(s0[10], s0[11]);
        unsigned d0 = pkb(s0[12], s0[13]), d1 = pkb(s0[14], s0[15]);
        plswap(c0, d0); plswap(c1, d1);
        u4 w1; w1[0] = c0; w1[1] = c1; w1[2] = d0; w1[3] = d1;
        pa[1] = __builtin_bit_cast(s8, w1);
    }

    // Y += P V  (V prefetched into regs one tile ago; no wait needed)
    __builtin_amdgcn_s_setprio(1);
#pragma unroll
    for (int ks = 0; ks < 2; ks++) {
        y0 = MFMA32B(pa[ks], vf[ks][0], y0);
        y1 = MFMA32B(pa[ks], vf[ks][1], y1);
    }
    __builtin_amdgcn_s_setprio(0);
}

__global__ __launch_bounds__(64) void attn_kernel(const f16* __restrict__ Q,
                                                  const f16* __restrict__ K,
                                                  const unsigned short* __restrict__ Vg,
                                                  f16* __restrict__ O) {
    __shared__ f16 lK[2][2048];  // [buf][32 rows x 64]
    const int lane = threadIdx.x;
    const int hi = lane >> 5, ln = lane & 31;
    const int bh = blockIdx.x & 63;
    const int p = (int)(blockIdx.x >> 6);  // 0..31
    const f16* Qb = Q + (size_t)bh * 2048 * 64;
    const f16* Kb = K + (size_t)bh * 2048 * 64;
    const unsigned short* Vb = Vg + (size_t)bh * 131072;
    const int b = bh >> 4, hh = bh & 15;

    for (int ph = 0; ph < 2; ph++) {
        const int qt = ph ? p : 63 - p;  // complementary pair: total 65 tiles/block, uniform
        const int qw = qt * 32;

        // hoist Q fragments (B-operand): Q[qw+ln][dd*16 + hi*8 .. +8]
        h8 qf[4];
#pragma unroll
        for (int dd = 0; dd < 4; dd++)
            qf[dd] = *(const h8*)(Qb + (size_t)(qw + ln) * 64 + dd * 16 + hi * 8);

        float lpart = 0.f;
        f16x y0, y1;
#pragma unroll
        for (int r = 0; r < 16; r++) { y0[r] = 0.f; y1[r] = 0.f; }

        const int nt = qt + 1;  // tiles of 32; last tile k0 == qw

        // prologue: stage K(0) -> lK[0], V(0) -> vfA
        s8 vfA[2][2], vfB[2][2];
#pragma unroll
        for (int i = 0; i < 4; i++) {
            int s = i * 64 + lane;
            int row = s >> 3;
            int gc = ((s & 7) ^ (row & 7)) * 8;
            gload16(Kb + (size_t)row * 64 + gc, &lK[0][i * 512]);
        }
#pragma unroll
        for (int ks = 0; ks < 2; ks++)
#pragma unroll
            for (int j = 0; j < 2; j++)
                vfA[ks][j] = *(const s8*)(Vb + (size_t)(j * 32 + ln) * 32 + ks * 16 + hi * 8);

        for (int it = 0; it < nt; it += 2) {
            attn_tile(it * 32, it == nt - 1, it + 1 < nt, lane, hi, ln, Kb, Vb,
                      &lK[0][0], &lK[1][0], qf, vfA, vfB, lpart, y0, y1);
            if (it + 1 < nt)
                attn_tile((it + 1) * 32, it + 1 == nt - 1, it + 2 < nt, lane, hi, ln, Kb, Vb,
                          &lK[1][0], &lK[0][0], qf, vfB, vfA, lpart, y0, y1);
        }

        // phase epilogue: combine half-lane partials, normalize, store
        float lT = lpart + __shfl_xor(lpart, 32);
        float inv = 1.0f / lT;
#pragma unroll
        for (int r = 0; r < 16; r++) {
            int crow = (r & 3) + 8 * (r >> 2) + 4 * hi;
            float invr = __shfl(inv, crow);
            size_t base = ((size_t)(b * 2048 + qw + crow)) * 1024 + hh * 64 + ln;
            O[base] = (f16)(y0[r] * invr);
            O[base + 32] = (f16)(y1[r] * invr);
        }
    }
}

// ---------------- launch ----------------

extern "C" void kernel_launch(void* const* d_in, const int* in_sizes, int n_in,
                              void* d_out, int out_size, void* d_ws, size_t ws_size,
                              hipStream_t stream) {
    const float* x      = (const float*)d_in[0];
    const float* W_attn = (const float*)d_in[1];
    const float* b_attn = (const float*)d_in[2];
    const float* W_proj = (const float*)d_in[3];
    const float* b_proj = (const float*)d_in[4];
    float* out = (float*)d_out;

    char* ws = (char*)d_ws;
    f16* xb  = (f16*)ws;                                   // 16 MB (reused as attn out)
    f16* Wat = (f16*)(ws + 16777216);                      // 6 MB
    f16* Wpt = (f16*)(ws + 16777216 + 6291456);            // 2 MB
    unsigned short* Vt = (unsigned short*)(ws + 16777216 + 6291456 + 2097152);  // 16 MB (bf16)
    f16* Qs  = (f16*)d_out;                                // scratch: first 16 MB of out
    f16* Ks  = (f16*)((char*)d_out + 16777216);            // scratch: second 16 MB of out

    cvt_f16_kernel<<<4096, 256, 0, stream>>>(x, xb, 1048576);
    transpose_cvt<<<dim3(96, 32), dim3(32, 8), 0, stream>>>(W_attn, Wat, 1024, 3072);
    transpose_cvt<<<dim3(32, 32), dim3(32, 8), 0, stream>>>(W_proj, Wpt, 1024, 1024);
    qkv_gemm<<<1536, 256, 0, stream>>>(xb, Wat, b_attn, Qs, Ks, Vt);
    attn_kernel<<<2048, 64, 0, stream>>>(Qs, Ks, Vt, xb);
    proj_gemm<<<512, 256, 0, stream>>>(xb, Wpt, b_proj, out);
}

// Round 24
// 173.452 us; speedup vs baseline: 1.0269x; 1.0269x over previous
//
#include <hip/hip_runtime.h>

typedef _Float16 f16;
typedef __attribute__((ext_vector_type(8))) _Float16 h8;
typedef __attribute__((ext_vector_type(4))) _Float16 h4;
typedef __attribute__((ext_vector_type(8))) short s8;     // 8 bf16 (4 VGPRs)
typedef __attribute__((ext_vector_type(4))) unsigned short u16x4;
typedef __attribute__((ext_vector_type(4))) float f4;
typedef __attribute__((ext_vector_type(16))) float f16x;
typedef __attribute__((ext_vector_type(4))) unsigned u4;

#define MFMA(a, b, c) __builtin_amdgcn_mfma_f32_16x16x32_f16(a, b, c, 0, 0, 0)
#define MFMA32(a, b, c) __builtin_amdgcn_mfma_f32_32x32x16_f16(a, b, c, 0, 0, 0)
#define MFMA32B(a, b, c) __builtin_amdgcn_mfma_f32_32x32x16_bf16(a, b, c, 0, 0, 0)

// Q prescale: 1/sqrt(64) * log2(e), folded into qkv epilogue -> softmax in base-2
#define QSCALE 0.18033688011112042f

#define ASM_VMCNT(N) asm volatile("s_waitcnt vmcnt(" #N ")" ::: "memory")

__device__ __forceinline__ void gload16(const void* g, void* l) {
    __builtin_amdgcn_global_load_lds((const __attribute__((address_space(1))) void*)g,
                                     (__attribute__((address_space(3))) void*)l, 16, 0, 0);
}

__device__ __forceinline__ float fexp2(float x) {
    float r;
    asm("v_exp_f32 %0, %1" : "=v"(r) : "v"(x));
    return r;
}

// pack 2 f32 -> 2 bf16 in one u32 (low = src0)
__device__ __forceinline__ unsigned pkb(float a, float b) {
    unsigned r;
    asm("v_cvt_pk_bf16_f32 %0, %1, %2" : "=v"(r) : "v"(a), "v"(b));
    return r;
}

// f32 -> bf16 with round-to-nearest-even
__device__ __forceinline__ unsigned short bf16rn(float x) {
    unsigned u = __builtin_bit_cast(unsigned, x);
    u += 0x7fffu + ((u >> 16) & 1u);
    return (unsigned short)(u >> 16);
}

// v_permlane32_swap_b32: a[l>=32] <-> b[l<32]  (both operands modified)
__device__ __forceinline__ void plswap(unsigned& a, unsigned& b) {
    asm volatile("v_permlane32_swap_b32 %0, %1" : "+v"(a), "+v"(b));
}

// ---------------- conversion kernels ----------------

__global__ __launch_bounds__(256) void cvt_f16_kernel(const float* __restrict__ in,
                                                      f16* __restrict__ out, int n8) {
    int i = blockIdx.x * blockDim.x + threadIdx.x;
    if (i >= n8) return;
    const float4* p = (const float4*)in + (size_t)i * 2;
    float4 a = p[0], b = p[1];
    h8 o;
    o[0] = (f16)a.x; o[1] = (f16)a.y; o[2] = (f16)a.z; o[3] = (f16)a.w;
    o[4] = (f16)b.x; o[5] = (f16)b.y; o[6] = (f16)b.z; o[7] = (f16)b.w;
    *((h8*)out + i) = o;
}

// in: [R][Cc] f32 row-major -> out: [Cc][R] f16 row-major
__global__ __launch_bounds__(256) void transpose_cvt(const float* __restrict__ in,
                                                     f16* __restrict__ out, int R, int Cc) {
    __shared__ float tile[32][33];
    int tx = threadIdx.x, ty = threadIdx.y;
    int c0 = blockIdx.x * 32, r0 = blockIdx.y * 32;
#pragma unroll
    for (int k = 0; k < 32; k += 8)
        tile[ty + k][tx] = in[(size_t)(r0 + ty + k) * Cc + c0 + tx];
    __syncthreads();
#pragma unroll
    for (int k = 0; k < 32; k += 8)
        out[(size_t)(c0 + ty + k) * R + r0 + tx] = (f16)tile[tx][ty + k];
}

// ---------------- GEMM core: 128x128 tile, BK=64, 8 WAVES (512 thr), 2-phase pipeline -------
// 8 waves partitioned 4M x 2N -> 32x64 output per wave (acc[2][4]); per-wave work halves,
// waves/CU doubles to 16 (4/SIMD) at the same 2-blocks/CU LDS residency -> TLP hides the
// step-top vmcnt latency. Skeleton identical to R22/R23: double-buffered LDS, per K-step:
//   vmcnt(0) | s_barrier | { ds_read; issue stage-half(t+1); MFMA } x2 | lgkmcnt(0); s_barrier

__device__ __forceinline__ void gemm_stage_half(const f16* __restrict__ M, int K, int r0, int k0,
                                                f16* dst, int tid, int wave) {
#pragma unroll
    for (int i = 0; i < 2; i++) {
        int s = i * 512 + tid;
        int row = s >> 3;
        int gc = ((s & 7) ^ (row & 7)) * 8;
        gload16(M + (size_t)(r0 + row) * K + k0 + gc, dst + (i * 512 + wave * 64) * 8);
    }
}

__device__ __forceinline__ void gemm_step(const f16* __restrict__ A, const f16* __restrict__ Bt,
                                          int K, int m0, int n0, int t, int nt,
                                          const f16* cA, const f16* cB, f16* nA, f16* nB,
                                          int tid, int lane, int wave, int wm, int wn,
                                          f4 acc[2][4]) {
    ASM_VMCNT(0);  // exactly tile-t's loads are outstanding here
    __builtin_amdgcn_sched_barrier(0);
    __builtin_amdgcn_s_barrier();
    __builtin_amdgcn_sched_barrier(0);
    const bool stage = (t + 1 < nt);
#pragma unroll
    for (int kk = 0; kk < 2; kk++) {
        h8 af[2], bg[4];
#pragma unroll
        for (int im = 0; im < 2; im++) {
            int row = wm + im * 16 + (lane & 15);
            int pc = (kk * 4 + (lane >> 4)) ^ (row & 7);
            af[im] = *(const h8*)(cA + row * 64 + pc * 8);
        }
#pragma unroll
        for (int in = 0; in < 4; in++) {
            int row = wn + in * 16 + (lane & 15);
            int pc = (kk * 4 + (lane >> 4)) ^ (row & 7);
            bg[in] = *(const h8*)(cB + row * 64 + pc * 8);
        }
        if (stage) {  // issue next-tile loads under this kk's MFMAs
            if (kk == 0) gemm_stage_half(A, K, m0, (t + 1) * 64, nA, tid, wave);
            else         gemm_stage_half(Bt, K, n0, (t + 1) * 64, nB, tid, wave);
        }
        __builtin_amdgcn_s_setprio(1);
#pragma unroll
        for (int im = 0; im < 2; im++)
#pragma unroll
            for (int in = 0; in < 4; in++)
                acc[im][in] = MFMA(af[im], bg[in], acc[im][in]);
        __builtin_amdgcn_s_setprio(0);
    }
    // all this wave's ds_reads of buf[cur] retired before signalling
    asm volatile("s_waitcnt lgkmcnt(0)" ::: "memory");
    __builtin_amdgcn_sched_barrier(0);
    __builtin_amdgcn_s_barrier();
    __builtin_amdgcn_sched_barrier(0);
}

__device__ __forceinline__ void gemm_core(const f16* __restrict__ A, const f16* __restrict__ Bt,
                                          int K, int m0, int n0,
                                          f16* lA0, f16* lB0, f16* lA1, f16* lB1,
                                          f4 acc[2][4]) {
    const int tid = threadIdx.x, lane = tid & 63, wave = tid >> 6;
    const int wm = (wave >> 1) * 32, wn = (wave & 1) * 64;  // 4M x 2N partition
    const int nt = K >> 6;  // 16 (even) for K=1024

    // prologue: stage tile 0 into buf 0 (completion enforced by step-0's vmcnt(0))
    gemm_stage_half(A, K, m0, 0, lA0, tid, wave);
    gemm_stage_half(Bt, K, n0, 0, lB0, tid, wave);

    for (int t = 0; t < nt; t += 2) {
        gemm_step(A, Bt, K, m0, n0, t, nt, lA0, lB0, lA1, lB1, tid, lane, wave, wm, wn, acc);
        gemm_step(A, Bt, K, m0, n0, t + 1, nt, lA1, lB1, lA0, lB0, tid, lane, wave, wm, wn, acc);
    }
}

// ---------------- QKV GEMM: Q (prescaled), K [BH][T][64] f16; V [BH][T/32][64][32] bf16 ----------------

__global__ __launch_bounds__(512) void qkv_gemm(const f16* __restrict__ A, const f16* __restrict__ Bt,
                                                const float* __restrict__ bias,
                                                f16* __restrict__ Qo, f16* __restrict__ Ko,
                                                unsigned short* __restrict__ Vo) {
    __shared__ f16 lA[2][128 * 64], lB[2][128 * 64];
    f4 acc[2][4];
    const f4 zz = {0.f, 0.f, 0.f, 0.f};
#pragma unroll
    for (int i = 0; i < 2; i++)
#pragma unroll
        for (int j = 0; j < 4; j++) acc[i][j] = zz;

    const int swz = (blockIdx.x & 7) * 192 + (blockIdx.x >> 3);  // XCD-chunked (1536 = 8*192)
    const int nb = swz % 24, mb = swz / 24;
    gemm_core(A, Bt, 1024, mb * 128, nb * 128, lA[0], lB[0], lA[1], lB[1], acc);

    const int lane = threadIdx.x & 63, wave = threadIdx.x >> 6;
    const int wm = (wave >> 1) * 32, wn = (wave & 1) * 64;
#pragma unroll
    for (int im = 0; im < 2; im++) {
        int m4 = mb * 128 + wm + im * 16 + (lane >> 4) * 4;
        int b = m4 >> 11, t0 = m4 & 2047;
#pragma unroll
        for (int in = 0; in < 4; in++) {
            int n = nb * 128 + wn + in * 16 + (lane & 15);
            float bb = bias[n];
            int sec = n >> 10, cc = n & 1023, hh = cc >> 6, d = cc & 63;
            if (sec == 2) {
                // V tiled [kt][64][32] bf16: addr = bh*131072 + (t/32)*2048 + d*32 + (t&31)
                u16x4 pv;
#pragma unroll
                for (int r = 0; r < 4; r++) pv[r] = bf16rn(acc[im][in][r] + bb);
                *(u16x4*)(Vo + (size_t)(b * 16 + hh) * 131072 + (t0 >> 5) * 2048 + d * 32 +
                          (t0 & 31)) = pv;
            } else {
                f16* dst = sec ? Ko : Qo;
                float sc = sec ? 1.0f : QSCALE;  // Q prescaled for base-2 softmax
                size_t base = ((size_t)(b * 16 + hh) * 2048 + t0) * 64 + d;
#pragma unroll
                for (int r = 0; r < 4; r++)
                    dst[base + (size_t)r * 64] = (f16)((acc[im][in][r] + bb) * sc);
            }
        }
    }
}

// ---------------- Proj GEMM: f32 output + bias ----------------

__global__ __launch_bounds__(512) void proj_gemm(const f16* __restrict__ A, const f16* __restrict__ Bt,
                                                 const float* __restrict__ bias,
                                                 float* __restrict__ out) {
    __shared__ f16 lA[2][128 * 64], lB[2][128 * 64];
    f4 acc[2][4];
    const f4 zz = {0.f, 0.f, 0.f, 0.f};
#pragma unroll
    for (int i = 0; i < 2; i++)
#pragma unroll
        for (int j = 0; j < 4; j++) acc[i][j] = zz;

    const int swz = (blockIdx.x & 7) * 64 + (blockIdx.x >> 3);  // XCD-chunked (512 = 8*64)
    const int nb = swz & 7, mb = swz >> 3;
    gemm_core(A, Bt, 1024, mb * 128, nb * 128, lA[0], lB[0], lA[1], lB[1], acc);

    const int lane = threadIdx.x & 63, wave = threadIdx.x >> 6;
    const int wm = (wave >> 1) * 32, wn = (wave & 1) * 64;
#pragma unroll
    for (int im = 0; im < 2; im++) {
        int m4 = mb * 128 + wm + im * 16 + (lane >> 4) * 4;
#pragma unroll
        for (int in = 0; in < 4; in++) {
            int n = nb * 128 + wn + in * 16 + (lane & 15);
            float bb = bias[n];
#pragma unroll
            for (int r = 0; r < 4; r++)
                out[(size_t)(m4 + r) * 1024 + n] = acc[im][in][r] + bb;
        }
    }
}

// ---------------- Flash attention: R21 winner (R18 packaging + kt-tiled V) ----------------

__device__ __forceinline__ void attn_tile(int k0, bool last, bool stage_next,
                                          int lane, int hi, int ln,
                                          const f16* __restrict__ Kb,
                                          const unsigned short* __restrict__ Vb,
                                          const f16* lKcur, f16* lKnxt,
                                          const h8 (&qf)[4], s8 (&vf)[2][2], s8 (&vfn)[2][2],
                                          float& lpart, f16x& y0, f16x& y1) {
    if (stage_next) {
        // K(it+1) -> other LDS buffer (4 x gload16)
#pragma unroll
        for (int i = 0; i < 4; i++) {
            int s = i * 64 + lane;
            int row = s >> 3;
            int gc = ((s & 7) ^ (row & 7)) * 8;
            gload16(Kb + (size_t)(k0 + 32 + row) * 64 + gc, lKnxt + i * 512);
        }
        // V(it+1) -> other register set (4 x dwordx4); kt-tiled: lane-consecutive lines
#pragma unroll
        for (int ks = 0; ks < 2; ks++)
#pragma unroll
            for (int j = 0; j < 2; j++)
                vfn[ks][j] = *(const s8*)(Vb + (size_t)((k0 >> 5) + 1) * 2048 +
                                          (j * 32 + ln) * 32 + ks * 16 + hi * 8);
        ASM_VMCNT(8);  // wait only last tile's 8 loads; current 8 stay in flight
    } else {
        ASM_VMCNT(0);
    }
    __builtin_amdgcn_sched_barrier(0);

    // S^T = K.Q^T (A = K rows from LDS, B = Q regs); lane owns q = qw+ln
    f16x s0;
#pragma unroll
    for (int r = 0; r < 16; r++) s0[r] = 0.f;
    __builtin_amdgcn_s_setprio(1);
#pragma unroll
    for (int dd = 0; dd < 4; dd++) {
        const int c = (dd * 2 + hi) ^ (ln & 7);  // swizzled 16B-chunk index
        h8 ka = *(const h8*)(lKcur + ln * 64 + c * 8);
        s0 = MFMA32(ka, qf[dd], s0);
    }
    __builtin_amdgcn_s_setprio(0);

    if (last) {  // diagonal tile (k0 == qw): mask k-local kl > ln
#pragma unroll
        for (int r = 0; r < 16; r++) {
            int kl = (r & 3) + 8 * (r >> 2) + 4 * hi;
            if (kl > ln) s0[r] = -3e38f;
        }
    }

    // no-shift softmax: P = 2^S (bf16 keeps relative precision at any scale)
    float ls = 0.f;
#pragma unroll
    for (int r = 0; r < 16; r++) {
        float p = fexp2(s0[r]);
        s0[r] = p;
        ls += p;
    }
    lpart += ls;

    // P -> PV A-fragments (bf16): 8 cvt_pk_bf16 + 4 permlane32_swap (layout HW-verified R9)
    s8 pa[2];
    {
        unsigned a0 = pkb(s0[0], s0[1]), a1 = pkb(s0[2], s0[3]);
        unsigned b0 = pkb(s0[4], s0[5]), b1 = pkb(s0[6], s0[7]);
        plswap(a0, b0); plswap(a1, b1);
        u4 w0; w0[0] = a0; w0[1] = a1; w0[2] = b0; w0[3] = b1;
        pa[0] = __builtin_bit_cast(s8, w0);
        unsigned c0 = pkb(s0[8], s0[9]), c1 = pkb(s0[10], s0[11]);
        unsigned d0 = pkb(s0[12], s0[13]), d1 = pkb(s0[14], s0[15]);
        plswap(c0, d0); plswap(c1, d1);
        u4 w1; w1[0] = c0; w1[1] = c1; w1[2] = d0; w1[3] = d1;
        pa[1] = __builtin_bit_cast(s8, w1);
    }

    // Y += P V  (V prefetched into regs one tile ago; no wait needed)
    __builtin_amdgcn_s_setprio(1);
#pragma unroll
    for (int ks = 0; ks < 2; ks++) {
        y0 = MFMA32B(pa[ks], vf[ks][0], y0);
        y1 = MFMA32B(pa[ks], vf[ks][1], y1);
    }
    __builtin_amdgcn_s_setprio(0);
}

__global__ __launch_bounds__(64) void attn_kernel(const f16* __restrict__ Q,
                                                  const f16* __restrict__ K,
                                                  const unsigned short* __restrict__ Vg,
                                                  f16* __restrict__ O) {
    __shared__ f16 lK[2][2048];  // [buf][32 rows x 64]
    const int lane = threadIdx.x;
    const int hi = lane >> 5, ln = lane & 31;
    const int bh = blockIdx.x & 63;
    const int p = (int)(blockIdx.x >> 6);  // 0..31
    const f16* Qb = Q + (size_t)bh * 2048 * 64;
    const f16* Kb = K + (size_t)bh * 2048 * 64;
    const unsigned short* Vb = Vg + (size_t)bh * 131072;
    const int b = bh >> 4, hh = bh & 15;

    for (int ph = 0; ph < 2; ph++) {
        const int qt = ph ? p : 63 - p;  // complementary pair: total 65 tiles/block, uniform
        const int qw = qt * 32;

        // hoist Q fragments (B-operand): Q[qw+ln][dd*16 + hi*8 .. +8]
        h8 qf[4];
#pragma unroll
        for (int dd = 0; dd < 4; dd++)
            qf[dd] = *(const h8*)(Qb + (size_t)(qw + ln) * 64 + dd * 16 + hi * 8);

        float lpart = 0.f;
        f16x y0, y1;
#pragma unroll
        for (int r = 0; r < 16; r++) { y0[r] = 0.f; y1[r] = 0.f; }

        const int nt = qt + 1;  // tiles of 32; last tile k0 == qw

        // prologue: stage K(0) -> lK[0], V(0) -> vfA
        s8 vfA[2][2], vfB[2][2];
#pragma unroll
        for (int i = 0; i < 4; i++) {
            int s = i * 64 + lane;
            int row = s >> 3;
            int gc = ((s & 7) ^ (row & 7)) * 8;
            gload16(Kb + (size_t)row * 64 + gc, &lK[0][i * 512]);
        }
#pragma unroll
        for (int ks = 0; ks < 2; ks++)
#pragma unroll
            for (int j = 0; j < 2; j++)
                vfA[ks][j] = *(const s8*)(Vb + (size_t)(j * 32 + ln) * 32 + ks * 16 + hi * 8);

        for (int it = 0; it < nt; it += 2) {
            attn_tile(it * 32, it == nt - 1, it + 1 < nt, lane, hi, ln, Kb, Vb,
                      &lK[0][0], &lK[1][0], qf, vfA, vfB, lpart, y0, y1);
            if (it + 1 < nt)
                attn_tile((it + 1) * 32, it + 1 == nt - 1, it + 2 < nt, lane, hi, ln, Kb, Vb,
                          &lK[1][0], &lK[0][0], qf, vfB, vfA, lpart, y0, y1);
        }

        // phase epilogue: combine half-lane partials, normalize, store
        float lT = lpart + __shfl_xor(lpart, 32);
        float inv = 1.0f / lT;
#pragma unroll
        for (int r = 0; r < 16; r++) {
            int crow = (r & 3) + 8 * (r >> 2) + 4 * hi;
            float invr = __shfl(inv, crow);
            size_t base = ((size_t)(b * 2048 + qw + crow)) * 1024 + hh * 64 + ln;
            O[base] = (f16)(y0[r] * invr);
            O[base + 32] = (f16)(y1[r] * invr);
        }
    }
}

// ---------------- launch ----------------

extern "C" void kernel_launch(void* const* d_in, const int* in_sizes, int n_in,
                              void* d_out, int out_size, void* d_ws, size_t ws_size,
                              hipStream_t stream) {
    const float* x      = (const float*)d_in[0];
    const float* W_attn = (const float*)d_in[1];
    const float* b_attn = (const float*)d_in[2];
    const float* W_proj = (const float*)d_in[3];
    const float* b_proj = (const float*)d_in[4];
    float* out = (float*)d_out;

    char* ws = (char*)d_ws;
    f16* xb  = (f16*)ws;                                   // 16 MB (reused as attn out)
    f16* Wat = (f16*)(ws + 16777216);                      // 6 MB
    f16* Wpt = (f16*)(ws + 16777216 + 6291456);            // 2 MB
    unsigned short* Vt = (unsigned short*)(ws + 16777216 + 6291456 + 2097152);  // 16 MB (bf16)
    f16* Qs  = (f16*)d_out;                                // scratch: first 16 MB of out
    f16* Ks  = (f16*)((char*)d_out + 16777216);            // scratch: second 16 MB of out

    cvt_f16_kernel<<<4096, 256, 0, stream>>>(x, xb, 1048576);
    transpose_cvt<<<dim3(96, 32), dim3(32, 8), 0, stream>>>(W_attn, Wat, 1024, 3072);
    transpose_cvt<<<dim3(32, 32), dim3(32, 8), 0, stream>>>(W_proj, Wpt, 1024, 1024);
    qkv_gemm<<<1536, 512, 0, stream>>>(xb, Wat, b_attn, Qs, Ks, Vt);
    attn_kernel<<<2048, 64, 0, stream>>>(Qs, Ks, Vt, xb);
    proj_gemm<<<512, 512, 0, stream>>>(xb, Wpt, b_proj, out);
}

// Round 25
// 172.871 us; speedup vs baseline: 1.0303x; 1.0034x over previous
//
#include <hip/hip_runtime.h>

typedef _Float16 f16;
typedef __attribute__((ext_vector_type(8))) _Float16 h8;
typedef __attribute__((ext_vector_type(4))) _Float16 h4;
typedef __attribute__((ext_vector_type(8))) short s8;     // 8 bf16 (4 VGPRs)
typedef __attribute__((ext_vector_type(4))) unsigned short u16x4;
typedef __attribute__((ext_vector_type(4))) float f4;
typedef __attribute__((ext_vector_type(16))) float f16x;
typedef __attribute__((ext_vector_type(4))) unsigned u4;

#define MFMA(a, b, c) __builtin_amdgcn_mfma_f32_16x16x32_f16(a, b, c, 0, 0, 0)
#define MFMA32(a, b, c) __builtin_amdgcn_mfma_f32_32x32x16_f16(a, b, c, 0, 0, 0)
#define MFMA32B(a, b, c) __builtin_amdgcn_mfma_f32_32x32x16_bf16(a, b, c, 0, 0, 0)

// Q prescale: 1/sqrt(64) * log2(e), folded into qkv epilogue -> softmax in base-2
#define QSCALE 0.18033688011112042f

#define ASM_VMCNT(N) asm volatile("s_waitcnt vmcnt(" #N ")" ::: "memory")

__device__ __forceinline__ void gload16(const void* g, void* l) {
    __builtin_amdgcn_global_load_lds((const __attribute__((address_space(1))) void*)g,
                                     (__attribute__((address_space(3))) void*)l, 16, 0, 0);
}

__device__ __forceinline__ float fexp2(float x) {
    float r;
    asm("v_exp_f32 %0, %1" : "=v"(r) : "v"(x));
    return r;
}

// pack 2 f32 -> 2 bf16 in one u32 (low = src0)
__device__ __forceinline__ unsigned pkb(float a, float b) {
    unsigned r;
    asm("v_cvt_pk_bf16_f32 %0, %1, %2" : "=v"(r) : "v"(a), "v"(b));
    return r;
}

// f32 -> bf16 with round-to-nearest-even
__device__ __forceinline__ unsigned short bf16rn(float x) {
    unsigned u = __builtin_bit_cast(unsigned, x);
    u += 0x7fffu + ((u >> 16) & 1u);
    return (unsigned short)(u >> 16);
}

// v_permlane32_swap_b32: a[l>=32] <-> b[l<32]  (both operands modified)
__device__ __forceinline__ void plswap(unsigned& a, unsigned& b) {
    asm volatile("v_permlane32_swap_b32 %0, %1" : "+v"(a), "+v"(b));
}

// ---------------- conversion kernels ----------------

__global__ __launch_bounds__(256) void cvt_f16_kernel(const float* __restrict__ in,
                                                      f16* __restrict__ out, int n8) {
    int i = blockIdx.x * blockDim.x + threadIdx.x;
    if (i >= n8) return;
    const float4* p = (const float4*)in + (size_t)i * 2;
    float4 a = p[0], b = p[1];
    h8 o;
    o[0] = (f16)a.x; o[1] = (f16)a.y; o[2] = (f16)a.z; o[3] = (f16)a.w;
    o[4] = (f16)b.x; o[5] = (f16)b.y; o[6] = (f16)b.z; o[7] = (f16)b.w;
    *((h8*)out + i) = o;
}

// in: [R][Cc] f32 row-major -> out: [Cc][R] f16 row-major
__global__ __launch_bounds__(256) void transpose_cvt(const float* __restrict__ in,
                                                     f16* __restrict__ out, int R, int Cc) {
    __shared__ float tile[32][33];
    int tx = threadIdx.x, ty = threadIdx.y;
    int c0 = blockIdx.x * 32, r0 = blockIdx.y * 32;
#pragma unroll
    for (int k = 0; k < 32; k += 8)
        tile[ty + k][tx] = in[(size_t)(r0 + ty + k) * Cc + c0 + tx];
    __syncthreads();
#pragma unroll
    for (int k = 0; k < 32; k += 8)
        out[(size_t)(c0 + ty + k) * R + r0 + tx] = (f16)tile[tx][ty + k];
}

// ---------------- GEMM core: 128x128 tile, BK=64, 8 waves (512 thr), SINGLE-barrier step ----
// Double-buffered LDS (2 x 32KB). Per K-step (one barrier only):
//   vmcnt(0)   -- tile-t's 8 loads (issued under step t-1's MFMAs) landed
//   lgkmcnt(0) -- my step t-1 ds_reads retired (free: MFMAs already consumed them)
//   s_barrier  -- all waves: tile-t visible AND everyone's t-1 reads done
//   { ds_read kk frags; issue stage-half(t+1 -> buf[other]); MFMA } x2
// Buffer safety: buf[other] was last read in step t-1; the barrier (with lgkmcnt before it)
// proves all waves retired those reads, so staging into it after the barrier is race-free.
// Tile-(t+1)'s loads stay in flight across the next barrier (counted-vmcnt property).

__device__ __forceinline__ void gemm_stage_half(const f16* __restrict__ M, int K, int r0, int k0,
                                                f16* dst, int tid, int wave) {
#pragma unroll
    for (int i = 0; i < 2; i++) {
        int s = i * 512 + tid;
        int row = s >> 3;
        int gc = ((s & 7) ^ (row & 7)) * 8;
        gload16(M + (size_t)(r0 + row) * K + k0 + gc, dst + (i * 512 + wave * 64) * 8);
    }
}

__device__ __forceinline__ void gemm_step(const f16* __restrict__ A, const f16* __restrict__ Bt,
                                          int K, int m0, int n0, int t, int nt,
                                          const f16* cA, const f16* cB, f16* nA, f16* nB,
                                          int tid, int lane, int wave, int wm, int wn,
                                          f4 acc[2][4]) {
    ASM_VMCNT(0);  // exactly tile-t's loads are outstanding here
    asm volatile("s_waitcnt lgkmcnt(0)" ::: "memory");  // step t-1 ds_reads retired
    __builtin_amdgcn_sched_barrier(0);
    __builtin_amdgcn_s_barrier();
    __builtin_amdgcn_sched_barrier(0);
    const bool stage = (t + 1 < nt);
#pragma unroll
    for (int kk = 0; kk < 2; kk++) {
        h8 af[2], bg[4];
#pragma unroll
        for (int im = 0; im < 2; im++) {
            int row = wm + im * 16 + (lane & 15);
            int pc = (kk * 4 + (lane >> 4)) ^ (row & 7);
            af[im] = *(const h8*)(cA + row * 64 + pc * 8);
        }
#pragma unroll
        for (int in = 0; in < 4; in++) {
            int row = wn + in * 16 + (lane & 15);
            int pc = (kk * 4 + (lane >> 4)) ^ (row & 7);
            bg[in] = *(const h8*)(cB + row * 64 + pc * 8);
        }
        if (stage) {  // issue next-tile loads under this kk's MFMAs
            if (kk == 0) gemm_stage_half(A, K, m0, (t + 1) * 64, nA, tid, wave);
            else         gemm_stage_half(Bt, K, n0, (t + 1) * 64, nB, tid, wave);
        }
        __builtin_amdgcn_s_setprio(1);
#pragma unroll
        for (int im = 0; im < 2; im++)
#pragma unroll
            for (int in = 0; in < 4; in++)
                acc[im][in] = MFMA(af[im], bg[in], acc[im][in]);
        __builtin_amdgcn_s_setprio(0);
    }
}

__device__ __forceinline__ void gemm_core(const f16* __restrict__ A, const f16* __restrict__ Bt,
                                          int K, int m0, int n0,
                                          f16* lA0, f16* lB0, f16* lA1, f16* lB1,
                                          f4 acc[2][4]) {
    const int tid = threadIdx.x, lane = tid & 63, wave = tid >> 6;
    const int wm = (wave >> 1) * 32, wn = (wave & 1) * 64;  // 4M x 2N partition
    const int nt = K >> 6;  // 16 (even) for K=1024

    // prologue: stage tile 0 into buf 0 (completion enforced by step-0's vmcnt(0))
    gemm_stage_half(A, K, m0, 0, lA0, tid, wave);
    gemm_stage_half(Bt, K, n0, 0, lB0, tid, wave);

    for (int t = 0; t < nt; t += 2) {
        gemm_step(A, Bt, K, m0, n0, t, nt, lA0, lB0, lA1, lB1, tid, lane, wave, wm, wn, acc);
        gemm_step(A, Bt, K, m0, n0, t + 1, nt, lA1, lB1, lA0, lB0, tid, lane, wave, wm, wn, acc);
    }
}

// ---------------- QKV GEMM: Q (prescaled), K [BH][T][64] f16; V [BH][T/32][64][32] bf16 ----------------

__global__ __launch_bounds__(512) void qkv_gemm(const f16* __restrict__ A, const f16* __restrict__ Bt,
                                                const float* __restrict__ bias,
                                                f16* __restrict__ Qo, f16* __restrict__ Ko,
                                                unsigned short* __restrict__ Vo) {
    __shared__ f16 lA[2][128 * 64], lB[2][128 * 64];
    f4 acc[2][4];
    const f4 zz = {0.f, 0.f, 0.f, 0.f};
#pragma unroll
    for (int i = 0; i < 2; i++)
#pragma unroll
        for (int j = 0; j < 4; j++) acc[i][j] = zz;

    const int swz = (blockIdx.x & 7) * 192 + (blockIdx.x >> 3);  // XCD-chunked (1536 = 8*192)
    const int nb = swz % 24, mb = swz / 24;
    gemm_core(A, Bt, 1024, mb * 128, nb * 128, lA[0], lB[0], lA[1], lB[1], acc);

    const int lane = threadIdx.x & 63, wave = threadIdx.x >> 6;
    const int wm = (wave >> 1) * 32, wn = (wave & 1) * 64;
#pragma unroll
    for (int im = 0; im < 2; im++) {
        int m4 = mb * 128 + wm + im * 16 + (lane >> 4) * 4;
        int b = m4 >> 11, t0 = m4 & 2047;
#pragma unroll
        for (int in = 0; in < 4; in++) {
            int n = nb * 128 + wn + in * 16 + (lane & 15);
            float bb = bias[n];
            int sec = n >> 10, cc = n & 1023, hh = cc >> 6, d = cc & 63;
            if (sec == 2) {
                // V tiled [kt][64][32] bf16: addr = bh*131072 + (t/32)*2048 + d*32 + (t&31)
                u16x4 pv;
#pragma unroll
                for (int r = 0; r < 4; r++) pv[r] = bf16rn(acc[im][in][r] + bb);
                *(u16x4*)(Vo + (size_t)(b * 16 + hh) * 131072 + (t0 >> 5) * 2048 + d * 32 +
                          (t0 & 31)) = pv;
            } else {
                f16* dst = sec ? Ko : Qo;
                float sc = sec ? 1.0f : QSCALE;  // Q prescaled for base-2 softmax
                size_t base = ((size_t)(b * 16 + hh) * 2048 + t0) * 64 + d;
#pragma unroll
                for (int r = 0; r < 4; r++)
                    dst[base + (size_t)r * 64] = (f16)((acc[im][in][r] + bb) * sc);
            }
        }
    }
}

// ---------------- Proj GEMM: f32 output + bias ----------------

__global__ __launch_bounds__(512) void proj_gemm(const f16* __restrict__ A, const f16* __restrict__ Bt,
                                                 const float* __restrict__ bias,
                                                 float* __restrict__ out) {
    __shared__ f16 lA[2][128 * 64], lB[2][128 * 64];
    f4 acc[2][4];
    const f4 zz = {0.f, 0.f, 0.f, 0.f};
#pragma unroll
    for (int i = 0; i < 2; i++)
#pragma unroll
        for (int j = 0; j < 4; j++) acc[i][j] = zz;

    const int swz = (blockIdx.x & 7) * 64 + (blockIdx.x >> 3);  // XCD-chunked (512 = 8*64)
    const int nb = swz & 7, mb = swz >> 3;
    gemm_core(A, Bt, 1024, mb * 128, nb * 128, lA[0], lB[0], lA[1], lB[1], acc);

    const int lane = threadIdx.x & 63, wave = threadIdx.x >> 6;
    const int wm = (wave >> 1) * 32, wn = (wave & 1) * 64;
#pragma unroll
    for (int im = 0; im < 2; im++) {
        int m4 = mb * 128 + wm + im * 16 + (lane >> 4) * 4;
#pragma unroll
        for (int in = 0; in < 4; in++) {
            int n = nb * 128 + wn + in * 16 + (lane & 15);
            float bb = bias[n];
#pragma unroll
            for (int r = 0; r < 4; r++)
                out[(size_t)(m4 + r) * 1024 + n] = acc[im][in][r] + bb;
        }
    }
}

// ---------------- Flash attention: R21 winner (R18 packaging + kt-tiled V) ----------------

__device__ __forceinline__ void attn_tile(int k0, bool last, bool stage_next,
                                          int lane, int hi, int ln,
                                          const f16* __restrict__ Kb,
                                          const unsigned short* __restrict__ Vb,
                                          const f16* lKcur, f16* lKnxt,
                                          const h8 (&qf)[4], s8 (&vf)[2][2], s8 (&vfn)[2][2],
                                          float& lpart, f16x& y0, f16x& y1) {
    if (stage_next) {
        // K(it+1) -> other LDS buffer (4 x gload16)
#pragma unroll
        for (int i = 0; i < 4; i++) {
            int s = i * 64 + lane;
            int row = s >> 3;
            int gc = ((s & 7) ^ (row & 7)) * 8;
            gload16(Kb + (size_t)(k0 + 32 + row) * 64 + gc, lKnxt + i * 512);
        }
        // V(it+1) -> other register set (4 x dwordx4); kt-tiled: lane-consecutive lines
#pragma unroll
        for (int ks = 0; ks < 2; ks++)
#pragma unroll
            for (int j = 0; j < 2; j++)
                vfn[ks][j] = *(const s8*)(Vb + (size_t)((k0 >> 5) + 1) * 2048 +
                                          (j * 32 + ln) * 32 + ks * 16 + hi * 8);
        ASM_VMCNT(8);  // wait only last tile's 8 loads; current 8 stay in flight
    } else {
        ASM_VMCNT(0);
    }
    __builtin_amdgcn_sched_barrier(0);

    // S^T = K.Q^T (A = K rows from LDS, B = Q regs); lane owns q = qw+ln
    f16x s0;
#pragma unroll
    for (int r = 0; r < 16; r++) s0[r] = 0.f;
    __builtin_amdgcn_s_setprio(1);
#pragma unroll
    for (int dd = 0; dd < 4; dd++) {
        const int c = (dd * 2 + hi) ^ (ln & 7);  // swizzled 16B-chunk index
        h8 ka = *(const h8*)(lKcur + ln * 64 + c * 8);
        s0 = MFMA32(ka, qf[dd], s0);
    }
    __builtin_amdgcn_s_setprio(0);

    if (last) {  // diagonal tile (k0 == qw): mask k-local kl > ln
#pragma unroll
        for (int r = 0; r < 16; r++) {
            int kl = (r & 3) + 8 * (r >> 2) + 4 * hi;
            if (kl > ln) s0[r] = -3e38f;
        }
    }

    // no-shift softmax: P = 2^S (bf16 keeps relative precision at any scale)
    float ls = 0.f;
#pragma unroll
    for (int r = 0; r < 16; r++) {
        float p = fexp2(s0[r]);
        s0[r] = p;
        ls += p;
    }
    lpart += ls;

    // P -> PV A-fragments (bf16): 8 cvt_pk_bf16 + 4 permlane32_swap (layout HW-verified R9)
    s8 pa[2];
    {
        unsigned a0 = pkb(s0[0], s0[1]), a1 = pkb(s0[2], s0[3]);
        unsigned b0 = pkb(s0[4], s0[5]), b1 = pkb(s0[6], s0[7]);
        plswap(a0, b0); plswap(a1, b1);
        u4 w0; w0[0] = a0; w0[1] = a1; w0[2] = b0; w0[3] = b1;
        pa[0] = __builtin_bit_cast(s8, w0);
        unsigned c0 = pkb(s0[8], s0[9]), c1 = pkb(s0[10], s0[11]);
        unsigned d0 = pkb(s0[12], s0[13]), d1 = pkb(s0[14], s0[15]);
        plswap(c0, d0); plswap(c1, d1);
        u4 w1; w1[0] = c0; w1[1] = c1; w1[2] = d0; w1[3] = d1;
        pa[1] = __builtin_bit_cast(s8, w1);
    }

    // Y += P V  (V prefetched into regs one tile ago; no wait needed)
    __builtin_amdgcn_s_setprio(1);
#pragma unroll
    for (int ks = 0; ks < 2; ks++) {
        y0 = MFMA32B(pa[ks], vf[ks][0], y0);
        y1 = MFMA32B(pa[ks], vf[ks][1], y1);
    }
    __builtin_amdgcn_s_setprio(0);
}

__global__ __launch_bounds__(64) void attn_kernel(const f16* __restrict__ Q,
                                                  const f16* __restrict__ K,
                                                  const unsigned short* __restrict__ Vg,
                                                  f16* __restrict__ O) {
    __shared__ f16 lK[2][2048];  // [buf][32 rows x 64]
    const int lane = threadIdx.x;
    const int hi = lane >> 5, ln = lane & 31;
    const int bh = blockIdx.x & 63;
    const int p = (int)(blockIdx.x >> 6);  // 0..31
    const f16* Qb = Q + (size_t)bh * 2048 * 64;
    const f16* Kb = K + (size_t)bh * 2048 * 64;
    const unsigned short* Vb = Vg + (size_t)bh * 131072;
    const int b = bh >> 4, hh = bh & 15;

    for (int ph = 0; ph < 2; ph++) {
        const int qt = ph ? p : 63 - p;  // complementary pair: total 65 tiles/block, uniform
        const int qw = qt * 32;

        // hoist Q fragments (B-operand): Q[qw+ln][dd*16 + hi*8 .. +8]
        h8 qf[4];
#pragma unroll
        for (int dd = 0; dd < 4; dd++)
            qf[dd] = *(const h8*)(Qb + (size_t)(qw + ln) * 64 + dd * 16 + hi * 8);

        float lpart = 0.f;
        f16x y0, y1;
#pragma unroll
        for (int r = 0; r < 16; r++) { y0[r] = 0.f; y1[r] = 0.f; }

        const int nt = qt + 1;  // tiles of 32; last tile k0 == qw

        // prologue: stage K(0) -> lK[0], V(0) -> vfA
        s8 vfA[2][2], vfB[2][2];
#pragma unroll
        for (int i = 0; i < 4; i++) {
            int s = i * 64 + lane;
            int row = s >> 3;
            int gc = ((s & 7) ^ (row & 7)) * 8;
            gload16(Kb + (size_t)row * 64 + gc, &lK[0][i * 512]);
        }
#pragma unroll
        for (int ks = 0; ks < 2; ks++)
#pragma unroll
            for (int j = 0; j < 2; j++)
                vfA[ks][j] = *(const s8*)(Vb + (size_t)(j * 32 + ln) * 32 + ks * 16 + hi * 8);

        for (int it = 0; it < nt; it += 2) {
            attn_tile(it * 32, it == nt - 1, it + 1 < nt, lane, hi, ln, Kb, Vb,
                      &lK[0][0], &lK[1][0], qf, vfA, vfB, lpart, y0, y1);
            if (it + 1 < nt)
                attn_tile((it + 1) * 32, it + 1 == nt - 1, it + 2 < nt, lane, hi, ln, Kb, Vb,
                          &lK[1][0], &lK[0][0], qf, vfB, vfA, lpart, y0, y1);
        }

        // phase epilogue: combine half-lane partials, normalize, store
        float lT = lpart + __shfl_xor(lpart, 32);
        float inv = 1.0f / lT;
#pragma unroll
        for (int r = 0; r < 16; r++) {
            int crow = (r & 3) + 8 * (r >> 2) + 4 * hi;
            float invr = __shfl(inv, crow);
            size_t base = ((size_t)(b * 2048 + qw + crow)) * 1024 + hh * 64 + ln;
            O[base] = (f16)(y0[r] * invr);
            O[base + 32] = (f16)(y1[r] * invr);
        }
    }
}

// ---------------- launch ----------------

extern "C" void kernel_launch(void* const* d_in, const int* in_sizes, int n_in,
                              void* d_out, int out_size, void* d_ws, size_t ws_size,
                              hipStream_t stream) {
    const float* x      = (const float*)d_in[0];
    const float* W_attn = (const float*)d_in[1];
    const float* b_attn = (const float*)d_in[2];
    const float* W_proj = (const float*)d_in[3];
    const float* b_proj = (const float*)d_in[4];
    float* out = (float*)d_out;

    char* ws = (char*)d_ws;
    f16* xb  = (f16*)ws;                                   // 16 MB (reused as attn out)
    f16* Wat = (f16*)(ws + 16777216);                      // 6 MB
    f16* Wpt = (f16*)(ws + 16777216 + 6291456);            // 2 MB
    unsigned short* Vt = (unsigned short*)(ws + 16777216 + 6291456 + 2097152);  // 16 MB (bf16)
    f16* Qs  = (f16*)d_out;                                // scratch: first 16 MB of out
    f16* Ks  = (f16*)((char*)d_out + 16777216);            // scratch: second 16 MB of out

    cvt_f16_kernel<<<4096, 256, 0, stream>>>(x, xb, 1048576);
    transpose_cvt<<<dim3(96, 32), dim3(32, 8), 0, stream>>>(W_attn, Wat, 1024, 3072);
    transpose_cvt<<<dim3(32, 32), dim3(32, 8), 0, stream>>>(W_proj, Wpt, 1024, 1024);
    qkv_gemm<<<1536, 512, 0, stream>>>(xb, Wat, b_attn, Qs, Ks, Vt);
    attn_kernel<<<2048, 64, 0, stream>>>(Qs, Ks, Vt, xb);
    proj_gemm<<<512, 512, 0, stream>>>(xb, Wpt, b_proj, out);
}